// Round 14
// baseline (493.122 us; speedup 1.0000x reference)
//
#include <hip/hip_runtime.h>
#include <hip/hip_fp16.h>
#include <math.h>

#define CUTOFF 5.0f
#define H 64
#define FIN 16
#define NLAYERS 3
#define LUTN 2048          // intervals; table has LUTN+1 entries
#define LUTSTRIDE 2052     // padded per-layer stride
#define ASTRIDE 72         // LDS row stride in halves (144B, 16B-aligned)
#define NPART 8            // histogram partitions
#define MEANB 256          // blocks in mean pass (partials rows)
#define LUTB 9             // lut blocks per layer (9*256 >= 2049)

// 1/sqrt(1 + 1e-3)  (BN inference, moving mean 0 / var 1)
#define BN_INV 0.999500374750f

typedef _Float16 h8 __attribute__((ext_vector_type(8)));
typedef _Float16 h2 __attribute__((ext_vector_type(2)));
typedef float f32x4 __attribute__((ext_vector_type(4)));

__device__ __forceinline__ float softplus_f(float x) {
    return fmaxf(x, 0.f) + __logf(1.f + __expf(-fabsf(x)));
}

// ---- K1: mega setup + histogram. Block roles by blockIdx range:
//   [0, nbEdge)              HIST: p = b&7, rank8[e] = atomic rank (cnt8 pre-zeroed)
//   [nbEdge, +nbE)           embed 4 nodes/block -> h0 fp16
//   [.., +27)                LUT: inline wsum/bsum in LDS, 256 entries/block
//   [.., +12)                weight swizzle Wsw + b2p
// Hist blocks are memory/atomic-latency-bound with ~0% VALU; setup compute
// co-schedules under them (separate waves overlap fully).
__global__ __launch_bounds__(256)
void k_setup(const int* __restrict__ ei, int* __restrict__ cnt8,
             unsigned char* __restrict__ rank8, int E,
             const float* __restrict__ x, const float* __restrict__ emb_W,
             const float* __restrict__ emb_b, _Float16* __restrict__ h0,
             const float* __restrict__ fW1, const float* __restrict__ fb1,
             const float* __restrict__ fW2, const float* __restrict__ fb2,
             const float* __restrict__ iW1, const float* __restrict__ iW2,
             const float* __restrict__ bn_g, const float* __restrict__ bn_b,
             const float* __restrict__ ib2, h8* __restrict__ Wsw,
             float* __restrict__ b2p, float* __restrict__ lut, int N) {
    __shared__ float swsum[64];
    __shared__ float sbsum;
    int b = blockIdx.x;
    int t = threadIdx.x;
    int nbEdge = (E + 255) / 256;
    int nbE = (N + 3) / 4;
    if (b < nbEdge) {
        int e = b * 256 + t;
        if (e < E) {
            int p = b & (NPART - 1);
            int r = atomicAdd(&cnt8[(size_t)p * N + ei[e]], 1);
            rank8[e] = (unsigned char)r;
        }
    } else if (b < nbEdge + nbE) {
        int b2 = b - nbEdge;
        int lane = t & 63;
        int w = t >> 6;
        int node = b2 * 4 + w;
        if (node < N) {
            float acc = emb_b[lane];
#pragma unroll
            for (int k = 0; k < FIN; k++) acc += x[node * FIN + k] * emb_W[k * H + lane];
            h0[(size_t)node * H + lane] = (_Float16)acc;
        }
    } else if (b < nbEdge + nbE + NLAYERS * LUTB) {
        int lb = b - nbEdge - nbE;
        int l = lb / LUTB, part = lb % LUTB;
        if (t < 64) {
            float s = 0.f;
            for (int j = 0; j < H; j++) s += fW2[l * H * H + t * H + j];
            swsum[t] = s;
        }
        if (t == 64) {
            float s = 0.f;
            for (int j = 0; j < H; j++) s += fb2[l * H + j];
            sbsum = s;
        }
        __syncthreads();
        int i = part * 256 + t;
        if (i <= LUTN) {
            float d = (float)i * (CUTOFF / (float)LUTN);
            float scaled = d * (2.0f / CUTOFF) - 1.0f;
            float cut = 0.5f * (__cosf(d * (3.14159265358979f / CUTOFF)) + 1.0f);
            if (d > CUTOFF) cut = 0.f;
            float s = 0.f;
            for (int hh = 0; hh < H; hh++) {
                int wi = l * H + hh;
                s += tanhf(scaled * fW1[wi] + fb1[wi]) * swsum[hh];
            }
            lut[l * LUTSTRIDE + i] = cut * (s + sbsum);
        }
    } else {
        int tid = (b - nbEdge - nbE - NLAYERS * LUTB) * 256 + t;
        if (tid < NLAYERS * H)
            b2p[tid] = ib2[tid] * BN_INV * bn_g[tid] + bn_b[tid];
        if (tid < NLAYERS * 2 * 8 * 64) {
            int lane = tid & 63;
            int frag = (tid >> 6) & 7;
            int mat  = (tid >> 9) & 1;
            int l    = tid >> 10;
            int kt = frag >> 2, nt = frag & 3;
            int n = nt * 16 + (lane & 15);
            int k0 = kt * 32 + (lane >> 4) * 8;
            const float* W = (mat ? iW2 : iW1) + l * H * H;
            float scale = mat ? BN_INV * bn_g[l * H + n] : 1.0f;
            h8 v;
#pragma unroll
            for (int j = 0; j < 8; j++) v[j] = (_Float16)(W[(k0 + j) * H + n] * scale);
            Wsw[tid] = v;
        }
    }
}

// scan stage 1: per-256-row block sums of the row totals (8 partitions summed)
__global__ void k_scan1(const int* __restrict__ cnt8, int* __restrict__ bsums, int N) {
    __shared__ int sd[256];
    int i = blockIdx.x * 256 + threadIdx.x;
    int v = 0;
    if (i < N) {
#pragma unroll
        for (int p = 0; p < NPART; p++) v += cnt8[(size_t)p * N + i];
    }
    sd[threadIdx.x] = v;
    __syncthreads();
    for (int off = 128; off > 0; off >>= 1) {
        if (threadIdx.x < off) sd[threadIdx.x] += sd[threadIdx.x + off];
        __syncthreads();
    }
    if (threadIdx.x == 0) bsums[blockIdx.x] = sd[0];
}

// scan stage 2+3 fused: every block redundantly scans the <=512 block sums in
// LDS, takes its own base, then per-block scan of row totals -> row_ptr and
// per-partition bases base[p][row].
__global__ void k_scan23(const int* __restrict__ cnt8, const int* __restrict__ bsums,
                         int* __restrict__ row_ptr, int* __restrict__ base,
                         int N, int nb) {
    __shared__ int sd[256];
    __shared__ int ex[512];
    int t = threadIdx.x;
    int a0 = (2 * t     < nb) ? bsums[2 * t]     : 0;
    int a1 = (2 * t + 1 < nb) ? bsums[2 * t + 1] : 0;
    sd[t] = a0 + a1;
    __syncthreads();
    for (int off = 1; off < 256; off <<= 1) {
        int v = (t >= off) ? sd[t - off] : 0;
        __syncthreads();
        sd[t] += v;
        __syncthreads();
    }
    int pairExcl = (t == 0) ? 0 : sd[t - 1];
    ex[2 * t] = pairExcl;
    ex[2 * t + 1] = pairExcl + a0;
    __syncthreads();
    int myBase = ex[blockIdx.x];
    __syncthreads();

    int i = blockIdx.x * 256 + t;
    int c[NPART];
    int v = 0;
    if (i < N) {
#pragma unroll
        for (int p = 0; p < NPART; p++) { c[p] = cnt8[(size_t)p * N + i]; v += c[p]; }
    }
    sd[t] = v;
    __syncthreads();
    for (int off = 1; off < 256; off <<= 1) {
        int u = (t >= off) ? sd[t - off] : 0;
        __syncthreads();
        sd[t] += u;
        __syncthreads();
    }
    int excl = sd[t] - v + myBase;
    if (i < N) {
        row_ptr[i] = excl;
        int run = excl;
#pragma unroll
        for (int p = 0; p < NPART; p++) { base[(size_t)p * N + i] = run; run += c[p]; }
        if (i == N - 1) row_ptr[N] = excl + v;
    }
}

// Thread-per-edge, no atomics: pos = base[p][row] + rank8[e] (p matches setup).
// Pack {col:17b | d_quant:15b}; nontemporal store (avoid line allocate).
__global__ __launch_bounds__(256)
void k_scatter(const int* __restrict__ ei, const float* __restrict__ dist,
               const unsigned char* __restrict__ rank8, const int* __restrict__ base,
               unsigned int* __restrict__ recs, int N, int E) {
    int e = blockIdx.x * 256 + threadIdx.x;
    if (e >= E) return;
    int p = blockIdx.x & (NPART - 1);
    int row = ei[e], col = ei[E + e];
    float d = dist[e];
    int didx = (int)(d * (32768.0f / CUTOFF) + 0.5f);
    didx = max(0, min(didx, 32767));
    int pos = base[(size_t)p * N + row] + (int)rank8[e];
    __builtin_nontemporal_store(((unsigned)col << 15) | (unsigned)didx, &recs[pos]);
}

// Fused layer, packed-fp16 phase A with 16 groups x 4 lanes: 16 edges in
// flight/wave, 2 uint4 gathers per lane (16 fp16 ch) -> 32 outstanding loads.
// fs lerped inline from LDS LUT. Phase B: 64x64x2 MLP as 16 MFMAs (fp16, BN
// folded in W2'). fp16 h double-buffered.
__global__ __launch_bounds__(256)
void k_layer(const int* __restrict__ row_ptr, const unsigned int* __restrict__ recs,
             const float* __restrict__ lutl, const h8* __restrict__ Wsw,
             const float* __restrict__ b1, const float* __restrict__ b2p,
             const _Float16* __restrict__ h_in, _Float16* __restrict__ h_out,
             int N) {
    __shared__ float s_lut[LUTN + 1];       // 8196 B
    __shared__ _Float16 sA[64 * ASTRIDE];   // 9216 B
    for (int i = threadIdx.x; i <= LUTN; i += 256) s_lut[i] = lutl[i];
    __syncthreads();

    int lane = threadIdx.x & 63;
    int w = threadIdx.x >> 6;
    int base = blockIdx.x * 64 + w * 16;    // this wave's 16 nodes
    int g = lane >> 2, ci = lane & 3;       // 16 groups x 4 lanes
    const uint4* h4 = (const uint4*)h_in;   // 8 halves per uint4; 8 per row

    // ---- phase A: aggregate (packed fp16, 16 edges in flight) ----
    for (int i = 0; i < 16; i++) {
        int node = base + i;
        h2 acc[8];
#pragma unroll
        for (int q = 0; q < 8; q++) acc[q] = (h2){(_Float16)0.f, (_Float16)0.f};
        if (node < N) {
            int s = row_ptr[node], t = row_ptr[node + 1];
            for (int k = s + g; k < t; k += 16) {
                unsigned rec = recs[k];
                int c = rec >> 15;
                float td = (float)(rec & 32767u) * (1.0f / 16.0f);
                int i0 = (int)td;
                float fr = td - (float)i0;
                float f0 = s_lut[i0];
                float fv = f0 + fr * (s_lut[i0 + 1] - f0);
                _Float16 fvh = (_Float16)fv;
                h2 fv2 = (h2){fvh, fvh};
                union { uint4 u; h2 v[4]; } p0, p1;
                p0.u = h4[(size_t)c * 8 + ci * 2];
                p1.u = h4[(size_t)c * 8 + ci * 2 + 1];
#pragma unroll
                for (int q = 0; q < 4; q++) acc[q]     += fv2 * p0.v[q];
#pragma unroll
                for (int q = 0; q < 4; q++) acc[4 + q] += fv2 * p1.v[q];
            }
        }
#pragma unroll
        for (int m = 4; m <= 32; m <<= 1) {
#pragma unroll
            for (int q = 0; q < 8; q++) {
                union { h2 v; int u; } a, b;
                a.v = acc[q];
                b.u = __shfl_xor(a.u, m, 64);
                acc[q] += b.v;
            }
        }
        if (g == 0) {
            union { uint4 u4; h2 v[4]; } pk0, pk1;
#pragma unroll
            for (int q = 0; q < 4; q++) { pk0.v[q] = acc[q]; pk1.v[q] = acc[4 + q]; }
            *(uint4*)&sA[(size_t)(w * 16 + i) * ASTRIDE + ci * 16] = pk0.u4;
            *(uint4*)&sA[(size_t)(w * 16 + i) * ASTRIDE + ci * 16 + 8] = pk1.u4;
        }
    }
    // wave-private LDS rows: in-wave ds ordering, no barrier needed

    // ---- phase B: MFMA MLP ----
    int q4 = lane >> 4, c16 = lane & 15;
    int rowb = w * 16;
    const h8* WB1 = Wsw;            // frags [kt][nt][lane]
    const h8* WB2 = Wsw + 8 * 64;
    h8 A0 = *(const h8*)&sA[(size_t)(rowb + c16) * ASTRIDE + q4 * 8];
    h8 A1 = *(const h8*)&sA[(size_t)(rowb + c16) * ASTRIDE + 32 + q4 * 8];
    f32x4 C1[4];
#pragma unroll
    for (int nt = 0; nt < 4; nt++) {
        f32x4 c = {0.f, 0.f, 0.f, 0.f};
        c = __builtin_amdgcn_mfma_f32_16x16x32_f16(A0, WB1[nt * 64 + lane], c, 0, 0, 0);
        c = __builtin_amdgcn_mfma_f32_16x16x32_f16(A1, WB1[(4 + nt) * 64 + lane], c, 0, 0, 0);
        C1[nt] = c;
    }
#pragma unroll
    for (int nt = 0; nt < 4; nt++) {
        float bb = b1[nt * 16 + c16];
#pragma unroll
        for (int reg = 0; reg < 4; reg++) {
            float v = softplus_f(C1[nt][reg] + bb);
            sA[(size_t)(rowb + q4 * 4 + reg) * ASTRIDE + nt * 16 + c16] = (_Float16)v;
        }
    }
    h8 M0 = *(const h8*)&sA[(size_t)(rowb + c16) * ASTRIDE + q4 * 8];
    h8 M1 = *(const h8*)&sA[(size_t)(rowb + c16) * ASTRIDE + 32 + q4 * 8];
    f32x4 C2[4];
#pragma unroll
    for (int nt = 0; nt < 4; nt++) {
        f32x4 c = {0.f, 0.f, 0.f, 0.f};
        c = __builtin_amdgcn_mfma_f32_16x16x32_f16(M0, WB2[nt * 64 + lane], c, 0, 0, 0);
        c = __builtin_amdgcn_mfma_f32_16x16x32_f16(M1, WB2[(4 + nt) * 64 + lane], c, 0, 0, 0);
        C2[nt] = c;
    }
    // epilogue: + b2' (BN folded), fp16 residual, dbuf write
#pragma unroll
    for (int nt = 0; nt < 4; nt++) {
        float bb2 = b2p[nt * 16 + c16];
#pragma unroll
        for (int reg = 0; reg < 4; reg++) {
            int node = base + q4 * 4 + reg;
            if (node < N) {
                size_t idx = (size_t)node * H + nt * 16 + c16;
                float hn = (float)h_in[idx] + C2[nt][reg] + bb2;
                h_out[idx] = (_Float16)hn;
            }
        }
    }
}

// Stage 1 of mean: per-block partial sums to DISTINCT rows — no atomics.
__global__ __launch_bounds__(256)
void k_mean(const _Float16* __restrict__ hb, float* __restrict__ partials, int N) {
    __shared__ float s_r[4][H];
    int lane = threadIdx.x & 63;
    int w = threadIdx.x >> 6;
    int wg = blockIdx.x * 4 + w;
    int stride = gridDim.x * 4;
    float local = 0.f;
    for (int i = wg; i < N; i += stride) local += (float)hb[(size_t)i * H + lane];
    s_r[w][lane] = local;
    __syncthreads();
    if (w == 0) {
        float s = s_r[0][lane] + s_r[1][lane] + s_r[2][lane] + s_r[3][lane];
        partials[(size_t)blockIdx.x * H + lane] = s;
    }
}

// Stage 2: one block reduces MEANB partial rows, then the tiny output MLP.
__global__ __launch_bounds__(256)
void k_final(const float* __restrict__ partials, int N,
             const float* __restrict__ oW1, const float* __restrict__ ob1,
             const float* __restrict__ og1, const float* __restrict__ obt1,
             const float* __restrict__ oW2, const float* __restrict__ ob2,
             const float* __restrict__ og2, const float* __restrict__ obt2,
             const float* __restrict__ fin_W, const float* __restrict__ fin_b,
             float* __restrict__ out) {
    __shared__ float red[4][H];
    __shared__ float sg[H], su[H / 2], sv[H / 2];
    int t = threadIdx.x;
    int ch = t & 63, grp = t >> 6;
    float s = 0.f;
    for (int b = grp; b < MEANB; b += 4) s += partials[(size_t)b * H + ch];
    red[grp][ch] = s;
    __syncthreads();
    if (t < H) sg[t] = (red[0][t] + red[1][t] + red[2][t] + red[3][t]) / (float)N;
    __syncthreads();
    int j = t;
    if (j < H / 2) {
        float acc = ob1[j];
        for (int k = 0; k < H; k++) acc += sg[k] * oW1[k * (H / 2) + j];
        su[j] = softplus_f(acc) * BN_INV * og1[j] + obt1[j];
    }
    __syncthreads();
    if (j < H / 2) {
        float acc = ob2[j];
        for (int k = 0; k < H / 2; k++) acc += su[k] * oW2[k * (H / 2) + j];
        sv[j] = softplus_f(acc) * BN_INV * og2[j] + obt2[j];
    }
    __syncthreads();
    if (j < 3) {
        float acc = fin_b[j];
        for (int k = 0; k < H / 2; k++) acc += sv[k] * fin_W[k * 3 + j];
        out[j] = acc;
    }
}

extern "C" void kernel_launch(void* const* d_in, const int* in_sizes, int n_in,
                              void* d_out, int out_size, void* d_ws, size_t ws_size,
                              hipStream_t stream) {
    const float* x      = (const float*)d_in[0];
    const int*   ei     = (const int*)d_in[1];
    const float* dist   = (const float*)d_in[2];
    /* d_in[3] edge_attr: unused by reference */
    const float* emb_W  = (const float*)d_in[4];
    const float* emb_b  = (const float*)d_in[5];
    const float* fW1    = (const float*)d_in[6];
    const float* fb1    = (const float*)d_in[7];
    const float* fW2    = (const float*)d_in[8];
    const float* fb2    = (const float*)d_in[9];
    const float* iW1    = (const float*)d_in[10];
    const float* ib1    = (const float*)d_in[11];
    const float* iW2    = (const float*)d_in[12];
    const float* ib2    = (const float*)d_in[13];
    const float* bn_g   = (const float*)d_in[14];
    const float* bn_b   = (const float*)d_in[15];
    const float* oW1    = (const float*)d_in[16];
    const float* ob1    = (const float*)d_in[17];
    const float* og1    = (const float*)d_in[18];
    const float* obt1   = (const float*)d_in[19];
    const float* oW2    = (const float*)d_in[20];
    const float* ob2    = (const float*)d_in[21];
    const float* og2    = (const float*)d_in[22];
    const float* obt2   = (const float*)d_in[23];
    const float* fin_W  = (const float*)d_in[24];
    const float* fin_b  = (const float*)d_in[25];
    float* out = (float*)d_out;

    int N = in_sizes[0] / FIN;
    int E = in_sizes[2];
    int nb_scan = (N + 255) / 256;
    int nb_edge = (E + 255) / 256;

    // workspace layout (16B-aligned chunks first)
    float*  ws   = (float*)d_ws;
    _Float16* h0 = (_Float16*)ws;                          // N*H fp16
    _Float16* h1 = h0 + (size_t)N * H;                     // N*H fp16
    unsigned int*  recs = (unsigned int*)(h1 + (size_t)N * H);   // E uint32
    h8*     Wsw  = (h8*)(recs + E);                        // 3*2*8*64 h8
    float*  lut  = (float*)(Wsw + NLAYERS * 2 * 8 * 64);   // 3*LUTSTRIDE
    float*  partials = lut + 3 * LUTSTRIDE;                // MEANB*H
    float*  b2p  = partials + MEANB * H;                   // L*H
    int*    cnt8 = (int*)(b2p + NLAYERS * H);              // NPART*N
    int*    basep = cnt8 + (size_t)NPART * N;              // NPART*N
    int*    row_ptr = basep + (size_t)NPART * N;           // N+1
    int*    bsums   = row_ptr + (N + 1);                   // nb_scan (<=512)
    unsigned char* rank8 = (unsigned char*)(bsums + 512);  // E bytes

    hipMemsetAsync(cnt8, 0, (size_t)NPART * N * sizeof(int), stream);

    int nbE = (N + 3) / 4;
    int nb_setup = nb_edge + nbE + NLAYERS * LUTB + 12;
    k_setup<<<nb_setup, 256, 0, stream>>>(ei, cnt8, rank8, E,
                                          x, emb_W, emb_b, h0,
                                          fW1, fb1, fW2, fb2, iW1, iW2,
                                          bn_g, bn_b, ib2, Wsw, b2p, lut, N);

    k_scan1<<<nb_scan, 256, 0, stream>>>(cnt8, bsums, N);
    k_scan23<<<nb_scan, 256, 0, stream>>>(cnt8, bsums, row_ptr, basep, N, nb_scan);

    k_scatter<<<nb_edge, 256, 0, stream>>>(ei, dist, rank8, basep, recs, N, E);

    _Float16* hp[2] = {h0, h1};
    int nb_tile = (N + 63) / 64;
    for (int l = 0; l < NLAYERS; l++) {
        k_layer<<<nb_tile, 256, 0, stream>>>(row_ptr, recs, lut + (size_t)l * LUTSTRIDE,
                                             Wsw + (size_t)l * 1024,
                                             ib1 + l * H, b2p + l * H,
                                             hp[l & 1], hp[(l + 1) & 1], N);
    }
    _Float16* h_final = hp[NLAYERS & 1];

    k_mean<<<MEANB, 256, 0, stream>>>(h_final, partials, N);
    k_final<<<1, 256, 0, stream>>>(partials, N, oW1, ob1, og1, obt1,
                                   oW2, ob2, og2, obt2, fin_W, fin_b, out);
}

// Round 15
// 492.913 us; speedup vs baseline: 1.0004x; 1.0004x over previous
//
#include <hip/hip_runtime.h>
#include <hip/hip_fp16.h>
#include <math.h>

#define CUTOFF 5.0f
#define H 64
#define FIN 16
#define NLAYERS 3
#define LUTN 2048          // intervals; table has LUTN+1 entries
#define LUTSTRIDE 2052     // padded per-layer stride
#define ASTRIDE 72         // LDS row stride in halves (144B, 16B-aligned)
#define NPART 8            // histogram partitions (== XCD count)
#define MEANB 256          // blocks in mean pass (partials rows)
#define LUTB 9             // lut blocks per layer (9*256 >= 2049)

// 1/sqrt(1 + 1e-3)  (BN inference, moving mean 0 / var 1)
#define BN_INV 0.999500374750f

typedef _Float16 h8 __attribute__((ext_vector_type(8)));
typedef _Float16 h2 __attribute__((ext_vector_type(2)));
typedef float f32x4 __attribute__((ext_vector_type(4)));

__device__ __forceinline__ float softplus_f(float x) {
    return fmaxf(x, 0.f) + __logf(1.f + __expf(-fabsf(x)));
}

// ---- K1: mega setup (R13 form — no hist). Block roles by blockIdx range:
//   [0, nbE)                 embed 4 nodes/block -> h0 fp16; zero 32 cnt8 ints
//   [nbE, nbE+27)            LUT: inline wsum/bsum in LDS, 256 entries/block
//   [nbE+27, nbE+39)         weight swizzle Wsw + b2p
__global__ __launch_bounds__(256)
void k_setup(const float* __restrict__ x, const float* __restrict__ emb_W,
             const float* __restrict__ emb_b, _Float16* __restrict__ h0,
             const float* __restrict__ fW1, const float* __restrict__ fb1,
             const float* __restrict__ fW2, const float* __restrict__ fb2,
             const float* __restrict__ iW1, const float* __restrict__ iW2,
             const float* __restrict__ bn_g, const float* __restrict__ bn_b,
             const float* __restrict__ ib2, h8* __restrict__ Wsw,
             float* __restrict__ b2p, float* __restrict__ lut,
             int* __restrict__ cnt8, int N) {
    __shared__ float swsum[64];
    __shared__ float sbsum;
    int b = blockIdx.x;
    int t = threadIdx.x;
    int nbE = (N + 3) / 4;
    if (b < nbE) {
        int ci = b * 32 + t;
        if (t < 32 && ci < NPART * N) cnt8[ci] = 0;
        int lane = t & 63;
        int w = t >> 6;
        int node = b * 4 + w;
        if (node < N) {
            float acc = emb_b[lane];
#pragma unroll
            for (int k = 0; k < FIN; k++) acc += x[node * FIN + k] * emb_W[k * H + lane];
            h0[(size_t)node * H + lane] = (_Float16)acc;
        }
    } else if (b < nbE + NLAYERS * LUTB) {
        int lb = b - nbE;
        int l = lb / LUTB, part = lb % LUTB;
        if (t < 64) {
            float s = 0.f;
            for (int j = 0; j < H; j++) s += fW2[l * H * H + t * H + j];
            swsum[t] = s;
        }
        if (t == 64) {
            float s = 0.f;
            for (int j = 0; j < H; j++) s += fb2[l * H + j];
            sbsum = s;
        }
        __syncthreads();
        int i = part * 256 + t;
        if (i <= LUTN) {
            float d = (float)i * (CUTOFF / (float)LUTN);
            float scaled = d * (2.0f / CUTOFF) - 1.0f;
            float cut = 0.5f * (__cosf(d * (3.14159265358979f / CUTOFF)) + 1.0f);
            if (d > CUTOFF) cut = 0.f;
            float s = 0.f;
            for (int hh = 0; hh < H; hh++) {
                int wi = l * H + hh;
                s += tanhf(scaled * fW1[wi] + fb1[wi]) * swsum[hh];
            }
            lut[l * LUTSTRIDE + i] = cut * (s + sbsum);
        }
    } else {
        int tid = (b - nbE - NLAYERS * LUTB) * 256 + t;
        if (tid < NLAYERS * H)
            b2p[tid] = ib2[tid] * BN_INV * bn_g[tid] + bn_b[tid];
        if (tid < NLAYERS * 2 * 8 * 64) {
            int lane = tid & 63;
            int frag = (tid >> 6) & 7;
            int mat  = (tid >> 9) & 1;
            int l    = tid >> 10;
            int kt = frag >> 2, nt = frag & 3;
            int n = nt * 16 + (lane & 15);
            int k0 = kt * 32 + (lane >> 4) * 8;
            const float* W = (mat ? iW2 : iW1) + l * H * H;
            float scale = mat ? BN_INV * bn_g[l * H + n] : 1.0f;
            h8 v;
#pragma unroll
            for (int j = 0; j < 8; j++) v[j] = (_Float16)(W[(k0 + j) * H + n] * scale);
            Wsw[tid] = v;
        }
    }
}

// Partitioned histogram: partition p = blockIdx%8. Atomic return value
// is the within-(partition,row) rank.
__global__ __launch_bounds__(256)
void k_hist(const int* __restrict__ ei, int* __restrict__ cnt8,
            unsigned char* __restrict__ rank8, int N, int E) {
    int e = blockIdx.x * 256 + threadIdx.x;
    if (e < E) {
        int p = blockIdx.x & (NPART - 1);
        int r = atomicAdd(&cnt8[(size_t)p * N + ei[e]], 1);
        rank8[e] = (unsigned char)r;
    }
}

// scan stage 1: per-256-row block sums of the row totals (8 partitions summed)
__global__ void k_scan1(const int* __restrict__ cnt8, int* __restrict__ bsums, int N) {
    __shared__ int sd[256];
    int i = blockIdx.x * 256 + threadIdx.x;
    int v = 0;
    if (i < N) {
#pragma unroll
        for (int p = 0; p < NPART; p++) v += cnt8[(size_t)p * N + i];
    }
    sd[threadIdx.x] = v;
    __syncthreads();
    for (int off = 128; off > 0; off >>= 1) {
        if (threadIdx.x < off) sd[threadIdx.x] += sd[threadIdx.x + off];
        __syncthreads();
    }
    if (threadIdx.x == 0) bsums[blockIdx.x] = sd[0];
}

// scan stage 2+3 fused: every block redundantly scans the <=512 block sums in
// LDS, takes its own base, then per-block scan of row totals -> row_ptr and
// per-partition bases base[p][row].
__global__ void k_scan23(const int* __restrict__ cnt8, const int* __restrict__ bsums,
                         int* __restrict__ row_ptr, int* __restrict__ base,
                         int N, int nb) {
    __shared__ int sd[256];
    __shared__ int ex[512];
    int t = threadIdx.x;
    int a0 = (2 * t     < nb) ? bsums[2 * t]     : 0;
    int a1 = (2 * t + 1 < nb) ? bsums[2 * t + 1] : 0;
    sd[t] = a0 + a1;
    __syncthreads();
    for (int off = 1; off < 256; off <<= 1) {
        int v = (t >= off) ? sd[t - off] : 0;
        __syncthreads();
        sd[t] += v;
        __syncthreads();
    }
    int pairExcl = (t == 0) ? 0 : sd[t - 1];
    ex[2 * t] = pairExcl;
    ex[2 * t + 1] = pairExcl + a0;
    __syncthreads();
    int myBase = ex[blockIdx.x];
    __syncthreads();

    int i = blockIdx.x * 256 + t;
    int c[NPART];
    int v = 0;
    if (i < N) {
#pragma unroll
        for (int p = 0; p < NPART; p++) { c[p] = cnt8[(size_t)p * N + i]; v += c[p]; }
    }
    sd[t] = v;
    __syncthreads();
    for (int off = 1; off < 256; off <<= 1) {
        int u = (t >= off) ? sd[t - off] : 0;
        __syncthreads();
        sd[t] += u;
        __syncthreads();
    }
    int excl = sd[t] - v + myBase;
    if (i < N) {
        row_ptr[i] = excl;
        int run = excl;
#pragma unroll
        for (int p = 0; p < NPART; p++) { base[(size_t)p * N + i] = run; run += c[p]; }
        if (i == N - 1) row_ptr[N] = excl + v;
    }
}

// Thread-per-edge, no atomics: pos = base[p][row] + rank8[e] (p matches k_hist).
// Pack {col:17b | d_quant:15b}; nontemporal store (avoid line allocate).
__global__ __launch_bounds__(256)
void k_scatter(const int* __restrict__ ei, const float* __restrict__ dist,
               const unsigned char* __restrict__ rank8, const int* __restrict__ base,
               unsigned int* __restrict__ recs, int N, int E) {
    int e = blockIdx.x * 256 + threadIdx.x;
    if (e >= E) return;
    int p = blockIdx.x & (NPART - 1);
    int row = ei[e], col = ei[E + e];
    float d = dist[e];
    int didx = (int)(d * (32768.0f / CUTOFF) + 0.5f);
    didx = max(0, min(didx, 32767));
    int pos = base[(size_t)p * N + row] + (int)rank8[e];
    __builtin_nontemporal_store(((unsigned)col << 15) | (unsigned)didx, &recs[pos]);
}

// Fused layer, packed-fp16 phase A with 16 groups x 4 lanes: 16 edges in
// flight/wave, 2 uint4 gathers per lane (16 fp16 ch) -> 32 outstanding loads.
// fs lerped inline from LDS LUT. Phase B: 64x64x2 MLP as 16 MFMAs (fp16, BN
// folded in W2'). fp16 h double-buffered.
__global__ __launch_bounds__(256)
void k_layer(const int* __restrict__ row_ptr, const unsigned int* __restrict__ recs,
             const float* __restrict__ lutl, const h8* __restrict__ Wsw,
             const float* __restrict__ b1, const float* __restrict__ b2p,
             const _Float16* __restrict__ h_in, _Float16* __restrict__ h_out,
             int N) {
    __shared__ float s_lut[LUTN + 1];       // 8196 B
    __shared__ _Float16 sA[64 * ASTRIDE];   // 9216 B
    for (int i = threadIdx.x; i <= LUTN; i += 256) s_lut[i] = lutl[i];
    __syncthreads();

    int lane = threadIdx.x & 63;
    int w = threadIdx.x >> 6;
    int base = blockIdx.x * 64 + w * 16;    // this wave's 16 nodes
    int g = lane >> 2, ci = lane & 3;       // 16 groups x 4 lanes
    const uint4* h4 = (const uint4*)h_in;   // 8 halves per uint4; 8 per row

    // ---- phase A: aggregate (packed fp16, 16 edges in flight) ----
    for (int i = 0; i < 16; i++) {
        int node = base + i;
        h2 acc[8];
#pragma unroll
        for (int q = 0; q < 8; q++) acc[q] = (h2){(_Float16)0.f, (_Float16)0.f};
        if (node < N) {
            int s = row_ptr[node], t = row_ptr[node + 1];
            for (int k = s + g; k < t; k += 16) {
                unsigned rec = recs[k];
                int c = rec >> 15;
                float td = (float)(rec & 32767u) * (1.0f / 16.0f);
                int i0 = (int)td;
                float fr = td - (float)i0;
                float f0 = s_lut[i0];
                float fv = f0 + fr * (s_lut[i0 + 1] - f0);
                _Float16 fvh = (_Float16)fv;
                h2 fv2 = (h2){fvh, fvh};
                union { uint4 u; h2 v[4]; } p0, p1;
                p0.u = h4[(size_t)c * 8 + ci * 2];
                p1.u = h4[(size_t)c * 8 + ci * 2 + 1];
#pragma unroll
                for (int q = 0; q < 4; q++) acc[q]     += fv2 * p0.v[q];
#pragma unroll
                for (int q = 0; q < 4; q++) acc[4 + q] += fv2 * p1.v[q];
            }
        }
#pragma unroll
        for (int m = 4; m <= 32; m <<= 1) {
#pragma unroll
            for (int q = 0; q < 8; q++) {
                union { h2 v; int u; } a, b;
                a.v = acc[q];
                b.u = __shfl_xor(a.u, m, 64);
                acc[q] += b.v;
            }
        }
        if (g == 0) {
            union { uint4 u4; h2 v[4]; } pk0, pk1;
#pragma unroll
            for (int q = 0; q < 4; q++) { pk0.v[q] = acc[q]; pk1.v[q] = acc[4 + q]; }
            *(uint4*)&sA[(size_t)(w * 16 + i) * ASTRIDE + ci * 16] = pk0.u4;
            *(uint4*)&sA[(size_t)(w * 16 + i) * ASTRIDE + ci * 16 + 8] = pk1.u4;
        }
    }
    // wave-private LDS rows: in-wave ds ordering, no barrier needed

    // ---- phase B: MFMA MLP ----
    int q4 = lane >> 4, c16 = lane & 15;
    int rowb = w * 16;
    const h8* WB1 = Wsw;            // frags [kt][nt][lane]
    const h8* WB2 = Wsw + 8 * 64;
    h8 A0 = *(const h8*)&sA[(size_t)(rowb + c16) * ASTRIDE + q4 * 8];
    h8 A1 = *(const h8*)&sA[(size_t)(rowb + c16) * ASTRIDE + 32 + q4 * 8];
    f32x4 C1[4];
#pragma unroll
    for (int nt = 0; nt < 4; nt++) {
        f32x4 c = {0.f, 0.f, 0.f, 0.f};
        c = __builtin_amdgcn_mfma_f32_16x16x32_f16(A0, WB1[nt * 64 + lane], c, 0, 0, 0);
        c = __builtin_amdgcn_mfma_f32_16x16x32_f16(A1, WB1[(4 + nt) * 64 + lane], c, 0, 0, 0);
        C1[nt] = c;
    }
#pragma unroll
    for (int nt = 0; nt < 4; nt++) {
        float bb = b1[nt * 16 + c16];
#pragma unroll
        for (int reg = 0; reg < 4; reg++) {
            float v = softplus_f(C1[nt][reg] + bb);
            sA[(size_t)(rowb + q4 * 4 + reg) * ASTRIDE + nt * 16 + c16] = (_Float16)v;
        }
    }
    h8 M0 = *(const h8*)&sA[(size_t)(rowb + c16) * ASTRIDE + q4 * 8];
    h8 M1 = *(const h8*)&sA[(size_t)(rowb + c16) * ASTRIDE + 32 + q4 * 8];
    f32x4 C2[4];
#pragma unroll
    for (int nt = 0; nt < 4; nt++) {
        f32x4 c = {0.f, 0.f, 0.f, 0.f};
        c = __builtin_amdgcn_mfma_f32_16x16x32_f16(M0, WB2[nt * 64 + lane], c, 0, 0, 0);
        c = __builtin_amdgcn_mfma_f32_16x16x32_f16(M1, WB2[(4 + nt) * 64 + lane], c, 0, 0, 0);
        C2[nt] = c;
    }
    // epilogue: + b2' (BN folded), fp16 residual, dbuf write
#pragma unroll
    for (int nt = 0; nt < 4; nt++) {
        float bb2 = b2p[nt * 16 + c16];
#pragma unroll
        for (int reg = 0; reg < 4; reg++) {
            int node = base + q4 * 4 + reg;
            if (node < N) {
                size_t idx = (size_t)node * H + nt * 16 + c16;
                float hn = (float)h_in[idx] + C2[nt][reg] + bb2;
                h_out[idx] = (_Float16)hn;
            }
        }
    }
}

// Stage 1 of mean: per-block partial sums to DISTINCT rows — no atomics.
__global__ __launch_bounds__(256)
void k_mean(const _Float16* __restrict__ hb, float* __restrict__ partials, int N) {
    __shared__ float s_r[4][H];
    int lane = threadIdx.x & 63;
    int w = threadIdx.x >> 6;
    int wg = blockIdx.x * 4 + w;
    int stride = gridDim.x * 4;
    float local = 0.f;
    for (int i = wg; i < N; i += stride) local += (float)hb[(size_t)i * H + lane];
    s_r[w][lane] = local;
    __syncthreads();
    if (w == 0) {
        float s = s_r[0][lane] + s_r[1][lane] + s_r[2][lane] + s_r[3][lane];
        partials[(size_t)blockIdx.x * H + lane] = s;
    }
}

// Stage 2: one block reduces MEANB partial rows, then the tiny output MLP.
__global__ __launch_bounds__(256)
void k_final(const float* __restrict__ partials, int N,
             const float* __restrict__ oW1, const float* __restrict__ ob1,
             const float* __restrict__ og1, const float* __restrict__ obt1,
             const float* __restrict__ oW2, const float* __restrict__ ob2,
             const float* __restrict__ og2, const float* __restrict__ obt2,
             const float* __restrict__ fin_W, const float* __restrict__ fin_b,
             float* __restrict__ out) {
    __shared__ float red[4][H];
    __shared__ float sg[H], su[H / 2], sv[H / 2];
    int t = threadIdx.x;
    int ch = t & 63, grp = t >> 6;
    float s = 0.f;
    for (int b = grp; b < MEANB; b += 4) s += partials[(size_t)b * H + ch];
    red[grp][ch] = s;
    __syncthreads();
    if (t < H) sg[t] = (red[0][t] + red[1][t] + red[2][t] + red[3][t]) / (float)N;
    __syncthreads();
    int j = t;
    if (j < H / 2) {
        float acc = ob1[j];
        for (int k = 0; k < H; k++) acc += sg[k] * oW1[k * (H / 2) + j];
        su[j] = softplus_f(acc) * BN_INV * og1[j] + obt1[j];
    }
    __syncthreads();
    if (j < H / 2) {
        float acc = ob2[j];
        for (int k = 0; k < H / 2; k++) acc += su[k] * oW2[k * (H / 2) + j];
        sv[j] = softplus_f(acc) * BN_INV * og2[j] + obt2[j];
    }
    __syncthreads();
    if (j < 3) {
        float acc = fin_b[j];
        for (int k = 0; k < H / 2; k++) acc += sv[k] * fin_W[k * 3 + j];
        out[j] = acc;
    }
}

extern "C" void kernel_launch(void* const* d_in, const int* in_sizes, int n_in,
                              void* d_out, int out_size, void* d_ws, size_t ws_size,
                              hipStream_t stream) {
    const float* x      = (const float*)d_in[0];
    const int*   ei     = (const int*)d_in[1];
    const float* dist   = (const float*)d_in[2];
    /* d_in[3] edge_attr: unused by reference */
    const float* emb_W  = (const float*)d_in[4];
    const float* emb_b  = (const float*)d_in[5];
    const float* fW1    = (const float*)d_in[6];
    const float* fb1    = (const float*)d_in[7];
    const float* fW2    = (const float*)d_in[8];
    const float* fb2    = (const float*)d_in[9];
    const float* iW1    = (const float*)d_in[10];
    const float* ib1    = (const float*)d_in[11];
    const float* iW2    = (const float*)d_in[12];
    const float* ib2    = (const float*)d_in[13];
    const float* bn_g   = (const float*)d_in[14];
    const float* bn_b   = (const float*)d_in[15];
    const float* oW1    = (const float*)d_in[16];
    const float* ob1    = (const float*)d_in[17];
    const float* og1    = (const float*)d_in[18];
    const float* obt1   = (const float*)d_in[19];
    const float* oW2    = (const float*)d_in[20];
    const float* ob2    = (const float*)d_in[21];
    const float* og2    = (const float*)d_in[22];
    const float* obt2   = (const float*)d_in[23];
    const float* fin_W  = (const float*)d_in[24];
    const float* fin_b  = (const float*)d_in[25];
    float* out = (float*)d_out;

    int N = in_sizes[0] / FIN;
    int E = in_sizes[2];
    int nb_scan = (N + 255) / 256;
    int nb_edge = (E + 255) / 256;

    // workspace layout (16B-aligned chunks first)
    float*  ws   = (float*)d_ws;
    _Float16* h0 = (_Float16*)ws;                          // N*H fp16
    _Float16* h1 = h0 + (size_t)N * H;                     // N*H fp16
    unsigned int*  recs = (unsigned int*)(h1 + (size_t)N * H);   // E uint32
    h8*     Wsw  = (h8*)(recs + E);                        // 3*2*8*64 h8
    float*  lut  = (float*)(Wsw + NLAYERS * 2 * 8 * 64);   // 3*LUTSTRIDE
    float*  partials = lut + 3 * LUTSTRIDE;                // MEANB*H
    float*  b2p  = partials + MEANB * H;                   // L*H
    int*    cnt8 = (int*)(b2p + NLAYERS * H);              // NPART*N
    int*    basep = cnt8 + (size_t)NPART * N;              // NPART*N
    int*    row_ptr = basep + (size_t)NPART * N;           // N+1
    int*    bsums   = row_ptr + (N + 1);                   // nb_scan (<=512)
    unsigned char* rank8 = (unsigned char*)(bsums + 512);  // E bytes

    int nbE = (N + 3) / 4;
    int nb_setup = nbE + NLAYERS * LUTB + 12;
    k_setup<<<nb_setup, 256, 0, stream>>>(x, emb_W, emb_b, h0,
                                          fW1, fb1, fW2, fb2, iW1, iW2,
                                          bn_g, bn_b, ib2, Wsw, b2p, lut,
                                          cnt8, N);

    k_hist<<<nb_edge, 256, 0, stream>>>(ei, cnt8, rank8, N, E);
    k_scan1<<<nb_scan, 256, 0, stream>>>(cnt8, bsums, N);
    k_scan23<<<nb_scan, 256, 0, stream>>>(cnt8, bsums, row_ptr, basep, N, nb_scan);

    k_scatter<<<nb_edge, 256, 0, stream>>>(ei, dist, rank8, basep, recs, N, E);

    _Float16* hp[2] = {h0, h1};
    int nb_tile = (N + 63) / 64;
    for (int l = 0; l < NLAYERS; l++) {
        k_layer<<<nb_tile, 256, 0, stream>>>(row_ptr, recs, lut + (size_t)l * LUTSTRIDE,
                                             Wsw + (size_t)l * 1024,
                                             ib1 + l * H, b2p + l * H,
                                             hp[l & 1], hp[(l + 1) & 1], N);
    }
    _Float16* h_final = hp[NLAYERS & 1];

    k_mean<<<MEANB, 256, 0, stream>>>(h_final, partials, N);
    k_final<<<1, 256, 0, stream>>>(partials, N, oW1, ob1, og1, obt1,
                                   oW2, ob2, og2, obt2, fin_W, fin_b, out);
}

// Round 16
// 479.686 us; speedup vs baseline: 1.0280x; 1.0276x over previous
//
#include <hip/hip_runtime.h>
#include <hip/hip_fp16.h>
#include <math.h>

#define CUTOFF 5.0f
#define H 64
#define FIN 16
#define NLAYERS 3
#define LUTN 2048          // intervals; table has LUTN+1 entries
#define LUTSTRIDE 2052     // padded per-layer stride
#define ASTRIDE 72         // LDS row stride in halves (144B, 16B-aligned)
#define NPART 8            // histogram partitions (== XCD count)
#define MEANB 256          // blocks in mean pass (partials rows)
#define LUTB 9             // lut blocks per layer (9*256 >= 2049)

// 1/sqrt(1 + 1e-3)  (BN inference, moving mean 0 / var 1)
#define BN_INV 0.999500374750f

typedef _Float16 h8 __attribute__((ext_vector_type(8)));
typedef float f32x2 __attribute__((ext_vector_type(2)));
typedef float f32x4 __attribute__((ext_vector_type(4)));

__device__ __forceinline__ float softplus_f(float x) {
    return fmaxf(x, 0.f) + __logf(1.f + __expf(-fabsf(x)));
}

__device__ __forceinline__ unsigned char to_fp8(float v) {
    return (unsigned char)(__builtin_amdgcn_cvt_pk_fp8_f32(v, v, 0, false) & 0xff);
}

// ---- K1: mega setup (R13 form). Block roles by blockIdx range:
//   [0, nbE)                 embed 4 nodes/block -> hb fp16 + hq fp8; zero 32 cnt8 ints
//   [nbE, nbE+27)            LUT: inline wsum/bsum in LDS, 256 entries/block
//   [nbE+27, nbE+39)         weight swizzle Wsw + b2p
__global__ __launch_bounds__(256)
void k_setup(const float* __restrict__ x, const float* __restrict__ emb_W,
             const float* __restrict__ emb_b, _Float16* __restrict__ hb,
             unsigned char* __restrict__ hq,
             const float* __restrict__ fW1, const float* __restrict__ fb1,
             const float* __restrict__ fW2, const float* __restrict__ fb2,
             const float* __restrict__ iW1, const float* __restrict__ iW2,
             const float* __restrict__ bn_g, const float* __restrict__ bn_b,
             const float* __restrict__ ib2, h8* __restrict__ Wsw,
             float* __restrict__ b2p, float* __restrict__ lut,
             int* __restrict__ cnt8, int N) {
    __shared__ float swsum[64];
    __shared__ float sbsum;
    int b = blockIdx.x;
    int t = threadIdx.x;
    int nbE = (N + 3) / 4;
    if (b < nbE) {
        int ci = b * 32 + t;
        if (t < 32 && ci < NPART * N) cnt8[ci] = 0;
        int lane = t & 63;
        int w = t >> 6;
        int node = b * 4 + w;
        if (node < N) {
            float acc = emb_b[lane];
#pragma unroll
            for (int k = 0; k < FIN; k++) acc += x[node * FIN + k] * emb_W[k * H + lane];
            size_t idx = (size_t)node * H + lane;
            hb[idx] = (_Float16)acc;
            hq[idx] = to_fp8(acc);
        }
    } else if (b < nbE + NLAYERS * LUTB) {
        int lb = b - nbE;
        int l = lb / LUTB, part = lb % LUTB;
        if (t < 64) {
            float s = 0.f;
            for (int j = 0; j < H; j++) s += fW2[l * H * H + t * H + j];
            swsum[t] = s;
        }
        if (t == 64) {
            float s = 0.f;
            for (int j = 0; j < H; j++) s += fb2[l * H + j];
            sbsum = s;
        }
        __syncthreads();
        int i = part * 256 + t;
        if (i <= LUTN) {
            float d = (float)i * (CUTOFF / (float)LUTN);
            float scaled = d * (2.0f / CUTOFF) - 1.0f;
            float cut = 0.5f * (__cosf(d * (3.14159265358979f / CUTOFF)) + 1.0f);
            if (d > CUTOFF) cut = 0.f;
            float s = 0.f;
            for (int hh = 0; hh < H; hh++) {
                int wi = l * H + hh;
                s += tanhf(scaled * fW1[wi] + fb1[wi]) * swsum[hh];
            }
            lut[l * LUTSTRIDE + i] = cut * (s + sbsum);
        }
    } else {
        int tid = (b - nbE - NLAYERS * LUTB) * 256 + t;
        if (tid < NLAYERS * H)
            b2p[tid] = ib2[tid] * BN_INV * bn_g[tid] + bn_b[tid];
        if (tid < NLAYERS * 2 * 8 * 64) {
            int lane = tid & 63;
            int frag = (tid >> 6) & 7;
            int mat  = (tid >> 9) & 1;
            int l    = tid >> 10;
            int kt = frag >> 2, nt = frag & 3;
            int n = nt * 16 + (lane & 15);
            int k0 = kt * 32 + (lane >> 4) * 8;
            const float* W = (mat ? iW2 : iW1) + l * H * H;
            float scale = mat ? BN_INV * bn_g[l * H + n] : 1.0f;
            h8 v;
#pragma unroll
            for (int j = 0; j < 8; j++) v[j] = (_Float16)(W[(k0 + j) * H + n] * scale);
            Wsw[tid] = v;
        }
    }
}

// Partitioned histogram: partition p = blockIdx%8. Atomic return value
// is the within-(partition,row) rank.
__global__ __launch_bounds__(256)
void k_hist(const int* __restrict__ ei, int* __restrict__ cnt8,
            unsigned char* __restrict__ rank8, int N, int E) {
    int e = blockIdx.x * 256 + threadIdx.x;
    if (e < E) {
        int p = blockIdx.x & (NPART - 1);
        int r = atomicAdd(&cnt8[(size_t)p * N + ei[e]], 1);
        rank8[e] = (unsigned char)r;
    }
}

// scan stage 1: per-256-row block sums of the row totals (8 partitions summed)
__global__ void k_scan1(const int* __restrict__ cnt8, int* __restrict__ bsums, int N) {
    __shared__ int sd[256];
    int i = blockIdx.x * 256 + threadIdx.x;
    int v = 0;
    if (i < N) {
#pragma unroll
        for (int p = 0; p < NPART; p++) v += cnt8[(size_t)p * N + i];
    }
    sd[threadIdx.x] = v;
    __syncthreads();
    for (int off = 128; off > 0; off >>= 1) {
        if (threadIdx.x < off) sd[threadIdx.x] += sd[threadIdx.x + off];
        __syncthreads();
    }
    if (threadIdx.x == 0) bsums[blockIdx.x] = sd[0];
}

// scan stage 2+3 fused: every block redundantly scans the <=512 block sums in
// LDS, takes its own base, then per-block scan of row totals -> row_ptr and
// per-partition bases base[p][row].
__global__ void k_scan23(const int* __restrict__ cnt8, const int* __restrict__ bsums,
                         int* __restrict__ row_ptr, int* __restrict__ base,
                         int N, int nb) {
    __shared__ int sd[256];
    __shared__ int ex[512];
    int t = threadIdx.x;
    int a0 = (2 * t     < nb) ? bsums[2 * t]     : 0;
    int a1 = (2 * t + 1 < nb) ? bsums[2 * t + 1] : 0;
    sd[t] = a0 + a1;
    __syncthreads();
    for (int off = 1; off < 256; off <<= 1) {
        int v = (t >= off) ? sd[t - off] : 0;
        __syncthreads();
        sd[t] += v;
        __syncthreads();
    }
    int pairExcl = (t == 0) ? 0 : sd[t - 1];
    ex[2 * t] = pairExcl;
    ex[2 * t + 1] = pairExcl + a0;
    __syncthreads();
    int myBase = ex[blockIdx.x];
    __syncthreads();

    int i = blockIdx.x * 256 + t;
    int c[NPART];
    int v = 0;
    if (i < N) {
#pragma unroll
        for (int p = 0; p < NPART; p++) { c[p] = cnt8[(size_t)p * N + i]; v += c[p]; }
    }
    sd[t] = v;
    __syncthreads();
    for (int off = 1; off < 256; off <<= 1) {
        int u = (t >= off) ? sd[t - off] : 0;
        __syncthreads();
        sd[t] += u;
        __syncthreads();
    }
    int excl = sd[t] - v + myBase;
    if (i < N) {
        row_ptr[i] = excl;
        int run = excl;
#pragma unroll
        for (int p = 0; p < NPART; p++) { base[(size_t)p * N + i] = run; run += c[p]; }
        if (i == N - 1) row_ptr[N] = excl + v;
    }
}

// Thread-per-edge, no atomics: pos = base[p][row] + rank8[e] (p matches k_hist).
// Pack {col:17b | d_quant:15b}; nontemporal store (avoid line allocate).
__global__ __launch_bounds__(256)
void k_scatter(const int* __restrict__ ei, const float* __restrict__ dist,
               const unsigned char* __restrict__ rank8, const int* __restrict__ base,
               unsigned int* __restrict__ recs, int N, int E) {
    int e = blockIdx.x * 256 + threadIdx.x;
    if (e >= E) return;
    int p = blockIdx.x & (NPART - 1);
    int row = ei[e], col = ei[E + e];
    float d = dist[e];
    int didx = (int)(d * (32768.0f / CUTOFF) + 0.5f);
    didx = max(0, min(didx, 32767));
    int pos = base[(size_t)p * N + row] + (int)rank8[e];
    __builtin_nontemporal_store(((unsigned)col << 15) | (unsigned)didx, &recs[pos]);
}

// Fused layer: phase A 8 groups x 8 lanes (R13 shape), fp8 gathers (64B row =
// 1 line, HW cvt_pk_f32_fp8 decode, pk_fma_f32 accumulate); fs lerped inline
// from LDS LUT. Phase B: 64x64x2 MLP as 16 MFMAs (fp16, BN folded in W2').
// fp16 residual master hb in-place (owner-only); fp8 shadow double-buffered.
__global__ __launch_bounds__(256)
void k_layer(const int* __restrict__ row_ptr, const unsigned int* __restrict__ recs,
             const float* __restrict__ lutl, const h8* __restrict__ Wsw,
             const float* __restrict__ b1, const float* __restrict__ b2p,
             const unsigned char* __restrict__ hq_in, unsigned char* __restrict__ hq_out,
             _Float16* __restrict__ hb, int N) {
    __shared__ float s_lut[LUTN + 1];       // 8196 B
    __shared__ _Float16 sA[64 * ASTRIDE];   // 9216 B
    for (int i = threadIdx.x; i <= LUTN; i += 256) s_lut[i] = lutl[i];
    __syncthreads();

    int lane = threadIdx.x & 63;
    int w = threadIdx.x >> 6;
    int base = blockIdx.x * 64 + w * 16;    // this wave's 16 nodes
    int g = lane >> 3, ci = lane & 7;       // 8 groups x 8 lanes

    // ---- phase A: aggregate (fp8 gather + HW decode + pk_fma_f32) ----
    for (int i = 0; i < 16; i++) {
        int node = base + i;
        f32x2 acc[4];
#pragma unroll
        for (int q = 0; q < 4; q++) acc[q] = (f32x2){0.f, 0.f};
        if (node < N) {
            int s = row_ptr[node], t = row_ptr[node + 1];
            for (int k = s + g; k < t; k += 8) {
                unsigned rec = recs[k];
                int c = rec >> 15;
                float td = (float)(rec & 32767u) * (1.0f / 16.0f);
                int i0 = (int)td;
                float fr = td - (float)i0;
                float f0 = s_lut[i0];
                float fv = f0 + fr * (s_lut[i0 + 1] - f0);
                f32x2 fv2 = (f32x2){fv, fv};
                union { uint2 u; unsigned int wo[2]; } pk;
                pk.u = *(const uint2*)(hq_in + (size_t)c * H + ci * 8);
                f32x2 c01 = __builtin_amdgcn_cvt_pk_f32_fp8(pk.wo[0], false);
                f32x2 c23 = __builtin_amdgcn_cvt_pk_f32_fp8(pk.wo[0], true);
                f32x2 c45 = __builtin_amdgcn_cvt_pk_f32_fp8(pk.wo[1], false);
                f32x2 c67 = __builtin_amdgcn_cvt_pk_f32_fp8(pk.wo[1], true);
                acc[0] += fv2 * c01;
                acc[1] += fv2 * c23;
                acc[2] += fv2 * c45;
                acc[3] += fv2 * c67;
            }
        }
#pragma unroll
        for (int m = 8; m <= 32; m <<= 1) {
#pragma unroll
            for (int q = 0; q < 4; q++) {
                f32x2 o;
                o.x = __shfl_xor(acc[q].x, m, 64);
                o.y = __shfl_xor(acc[q].y, m, 64);
                acc[q] += o;
            }
        }
        if (g == 0) {
            union { uint4 u4; _Float16 hh[8]; } pk;
#pragma unroll
            for (int q = 0; q < 4; q++) {
                pk.hh[2 * q]     = (_Float16)acc[q].x;
                pk.hh[2 * q + 1] = (_Float16)acc[q].y;
            }
            *(uint4*)&sA[(size_t)(w * 16 + i) * ASTRIDE + ci * 8] = pk.u4;
        }
    }
    // wave-private LDS rows: in-wave ds ordering, no barrier needed

    // ---- phase B: MFMA MLP ----
    int q4 = lane >> 4, c16 = lane & 15;
    int rowb = w * 16;
    const h8* WB1 = Wsw;            // frags [kt][nt][lane]
    const h8* WB2 = Wsw + 8 * 64;
    h8 A0 = *(const h8*)&sA[(size_t)(rowb + c16) * ASTRIDE + q4 * 8];
    h8 A1 = *(const h8*)&sA[(size_t)(rowb + c16) * ASTRIDE + 32 + q4 * 8];
    f32x4 C1[4];
#pragma unroll
    for (int nt = 0; nt < 4; nt++) {
        f32x4 c = {0.f, 0.f, 0.f, 0.f};
        c = __builtin_amdgcn_mfma_f32_16x16x32_f16(A0, WB1[nt * 64 + lane], c, 0, 0, 0);
        c = __builtin_amdgcn_mfma_f32_16x16x32_f16(A1, WB1[(4 + nt) * 64 + lane], c, 0, 0, 0);
        C1[nt] = c;
    }
#pragma unroll
    for (int nt = 0; nt < 4; nt++) {
        float bb = b1[nt * 16 + c16];
#pragma unroll
        for (int reg = 0; reg < 4; reg++) {
            float v = softplus_f(C1[nt][reg] + bb);
            sA[(size_t)(rowb + q4 * 4 + reg) * ASTRIDE + nt * 16 + c16] = (_Float16)v;
        }
    }
    h8 M0 = *(const h8*)&sA[(size_t)(rowb + c16) * ASTRIDE + q4 * 8];
    h8 M1 = *(const h8*)&sA[(size_t)(rowb + c16) * ASTRIDE + 32 + q4 * 8];
    f32x4 C2[4];
#pragma unroll
    for (int nt = 0; nt < 4; nt++) {
        f32x4 c = {0.f, 0.f, 0.f, 0.f};
        c = __builtin_amdgcn_mfma_f32_16x16x32_f16(M0, WB2[nt * 64 + lane], c, 0, 0, 0);
        c = __builtin_amdgcn_mfma_f32_16x16x32_f16(M1, WB2[(4 + nt) * 64 + lane], c, 0, 0, 0);
        C2[nt] = c;
    }
    // epilogue: + b2' (BN folded), fp16 in-place residual, fp8 shadow out
#pragma unroll
    for (int nt = 0; nt < 4; nt++) {
        float bb2 = b2p[nt * 16 + c16];
#pragma unroll
        for (int reg = 0; reg < 4; reg++) {
            int node = base + q4 * 4 + reg;
            if (node < N) {
                size_t idx = (size_t)node * H + nt * 16 + c16;
                float hn = (float)hb[idx] + C2[nt][reg] + bb2;
                hb[idx] = (_Float16)hn;
                hq_out[idx] = to_fp8(hn);
            }
        }
    }
}

// Stage 1 of mean: per-block partial sums to DISTINCT rows — no atomics.
__global__ __launch_bounds__(256)
void k_mean(const _Float16* __restrict__ hb, float* __restrict__ partials, int N) {
    __shared__ float s_r[4][H];
    int lane = threadIdx.x & 63;
    int w = threadIdx.x >> 6;
    int wg = blockIdx.x * 4 + w;
    int stride = gridDim.x * 4;
    float local = 0.f;
    for (int i = wg; i < N; i += stride) local += (float)hb[(size_t)i * H + lane];
    s_r[w][lane] = local;
    __syncthreads();
    if (w == 0) {
        float s = s_r[0][lane] + s_r[1][lane] + s_r[2][lane] + s_r[3][lane];
        partials[(size_t)blockIdx.x * H + lane] = s;
    }
}

// Stage 2: one block reduces MEANB partial rows, then the tiny output MLP.
__global__ __launch_bounds__(256)
void k_final(const float* __restrict__ partials, int N,
             const float* __restrict__ oW1, const float* __restrict__ ob1,
             const float* __restrict__ og1, const float* __restrict__ obt1,
             const float* __restrict__ oW2, const float* __restrict__ ob2,
             const float* __restrict__ og2, const float* __restrict__ obt2,
             const float* __restrict__ fin_W, const float* __restrict__ fin_b,
             float* __restrict__ out) {
    __shared__ float red[4][H];
    __shared__ float sg[H], su[H / 2], sv[H / 2];
    int t = threadIdx.x;
    int ch = t & 63, grp = t >> 6;
    float s = 0.f;
    for (int b = grp; b < MEANB; b += 4) s += partials[(size_t)b * H + ch];
    red[grp][ch] = s;
    __syncthreads();
    if (t < H) sg[t] = (red[0][t] + red[1][t] + red[2][t] + red[3][t]) / (float)N;
    __syncthreads();
    int j = t;
    if (j < H / 2) {
        float acc = ob1[j];
        for (int k = 0; k < H; k++) acc += sg[k] * oW1[k * (H / 2) + j];
        su[j] = softplus_f(acc) * BN_INV * og1[j] + obt1[j];
    }
    __syncthreads();
    if (j < H / 2) {
        float acc = ob2[j];
        for (int k = 0; k < H / 2; k++) acc += su[k] * oW2[k * (H / 2) + j];
        sv[j] = softplus_f(acc) * BN_INV * og2[j] + obt2[j];
    }
    __syncthreads();
    if (j < 3) {
        float acc = fin_b[j];
        for (int k = 0; k < H / 2; k++) acc += sv[k] * fin_W[k * 3 + j];
        out[j] = acc;
    }
}

extern "C" void kernel_launch(void* const* d_in, const int* in_sizes, int n_in,
                              void* d_out, int out_size, void* d_ws, size_t ws_size,
                              hipStream_t stream) {
    const float* x      = (const float*)d_in[0];
    const int*   ei     = (const int*)d_in[1];
    const float* dist   = (const float*)d_in[2];
    /* d_in[3] edge_attr: unused by reference */
    const float* emb_W  = (const float*)d_in[4];
    const float* emb_b  = (const float*)d_in[5];
    const float* fW1    = (const float*)d_in[6];
    const float* fb1    = (const float*)d_in[7];
    const float* fW2    = (const float*)d_in[8];
    const float* fb2    = (const float*)d_in[9];
    const float* iW1    = (const float*)d_in[10];
    const float* ib1    = (const float*)d_in[11];
    const float* iW2    = (const float*)d_in[12];
    const float* ib2    = (const float*)d_in[13];
    const float* bn_g   = (const float*)d_in[14];
    const float* bn_b   = (const float*)d_in[15];
    const float* oW1    = (const float*)d_in[16];
    const float* ob1    = (const float*)d_in[17];
    const float* og1    = (const float*)d_in[18];
    const float* obt1   = (const float*)d_in[19];
    const float* oW2    = (const float*)d_in[20];
    const float* ob2    = (const float*)d_in[21];
    const float* og2    = (const float*)d_in[22];
    const float* obt2   = (const float*)d_in[23];
    const float* fin_W  = (const float*)d_in[24];
    const float* fin_b  = (const float*)d_in[25];
    float* out = (float*)d_out;

    int N = in_sizes[0] / FIN;
    int E = in_sizes[2];
    int nb_scan = (N + 255) / 256;
    int nb_edge = (E + 255) / 256;

    // workspace layout (16B-aligned chunks first)
    float*  ws   = (float*)d_ws;
    _Float16* hb = (_Float16*)ws;                          // N*H fp16 (in-place master)
    unsigned char* hq0 = (unsigned char*)(hb + (size_t)N * H);   // N*H fp8
    unsigned char* hq1 = hq0 + (size_t)N * H;                    // N*H fp8
    unsigned int*  recs = (unsigned int*)(hq1 + (size_t)N * H);  // E uint32
    h8*     Wsw  = (h8*)(recs + E);                        // 3*2*8*64 h8
    float*  lut  = (float*)(Wsw + NLAYERS * 2 * 8 * 64);   // 3*LUTSTRIDE
    float*  partials = lut + 3 * LUTSTRIDE;                // MEANB*H
    float*  b2p  = partials + MEANB * H;                   // L*H
    int*    cnt8 = (int*)(b2p + NLAYERS * H);              // NPART*N
    int*    basep = cnt8 + (size_t)NPART * N;              // NPART*N
    int*    row_ptr = basep + (size_t)NPART * N;           // N+1
    int*    bsums   = row_ptr + (N + 1);                   // nb_scan (<=512)
    unsigned char* rank8 = (unsigned char*)(bsums + 512);  // E bytes

    int nbE = (N + 3) / 4;
    int nb_setup = nbE + NLAYERS * LUTB + 12;
    k_setup<<<nb_setup, 256, 0, stream>>>(x, emb_W, emb_b, hb, hq0,
                                          fW1, fb1, fW2, fb2, iW1, iW2,
                                          bn_g, bn_b, ib2, Wsw, b2p, lut,
                                          cnt8, N);

    k_hist<<<nb_edge, 256, 0, stream>>>(ei, cnt8, rank8, N, E);
    k_scan1<<<nb_scan, 256, 0, stream>>>(cnt8, bsums, N);
    k_scan23<<<nb_scan, 256, 0, stream>>>(cnt8, bsums, row_ptr, basep, N, nb_scan);

    k_scatter<<<nb_edge, 256, 0, stream>>>(ei, dist, rank8, basep, recs, N, E);

    unsigned char* hqp[2] = {hq0, hq1};
    int nb_tile = (N + 63) / 64;
    for (int l = 0; l < NLAYERS; l++) {
        k_layer<<<nb_tile, 256, 0, stream>>>(row_ptr, recs, lut + (size_t)l * LUTSTRIDE,
                                             Wsw + (size_t)l * 1024,
                                             ib1 + l * H, b2p + l * H,
                                             hqp[l & 1], hqp[(l + 1) & 1], hb, N);
    }

    k_mean<<<MEANB, 256, 0, stream>>>(hb, partials, N);
    k_final<<<1, 256, 0, stream>>>(partials, N, oW1, ob1, og1, obt1,
                                   oW2, ob2, og2, obt2, fin_W, fin_b, out);
}

// Round 17
// 438.212 us; speedup vs baseline: 1.1253x; 1.0946x over previous
//
#include <hip/hip_runtime.h>
#include <hip/hip_fp16.h>
#include <math.h>

#define CUTOFF 5.0f
#define H 64
#define FIN 16
#define NLAYERS 3
#define LUTN 2048          // intervals; table has LUTN+1 entries
#define LUTSTRIDE 2052     // padded per-layer stride
#define ASTRIDE 72         // LDS row stride in halves (144B, 16B-aligned)
#define NPART 8            // histogram partitions (== XCD count)
#define MEANB 256          // blocks in mean pass (partials rows)
#define LUTB 9             // lut blocks per layer (9*256 >= 2049)

// 1/sqrt(1 + 1e-3)  (BN inference, moving mean 0 / var 1)
#define BN_INV 0.999500374750f

typedef _Float16 h8 __attribute__((ext_vector_type(8)));
typedef _Float16 h2 __attribute__((ext_vector_type(2)));
typedef float f32x4 __attribute__((ext_vector_type(4)));

__device__ __forceinline__ float softplus_f(float x) {
    return fmaxf(x, 0.f) + __logf(1.f + __expf(-fabsf(x)));
}

// ---- K1: mega setup (R13 form). Block roles by blockIdx range:
//   [0, nbE)                 embed 4 nodes/block -> h0 fp16; zero 32 cnt8 ints
//   [nbE, nbE+27)            LUT: inline wsum/bsum in LDS, 256 entries/block
//   [nbE+27, nbE+39)         weight swizzle Wsw + b2p
__global__ __launch_bounds__(256)
void k_setup(const float* __restrict__ x, const float* __restrict__ emb_W,
             const float* __restrict__ emb_b, _Float16* __restrict__ h0,
             const float* __restrict__ fW1, const float* __restrict__ fb1,
             const float* __restrict__ fW2, const float* __restrict__ fb2,
             const float* __restrict__ iW1, const float* __restrict__ iW2,
             const float* __restrict__ bn_g, const float* __restrict__ bn_b,
             const float* __restrict__ ib2, h8* __restrict__ Wsw,
             float* __restrict__ b2p, float* __restrict__ lut,
             int* __restrict__ cnt8, int N) {
    __shared__ float swsum[64];
    __shared__ float sbsum;
    int b = blockIdx.x;
    int t = threadIdx.x;
    int nbE = (N + 3) / 4;
    if (b < nbE) {
        int ci = b * 32 + t;
        if (t < 32 && ci < NPART * N) cnt8[ci] = 0;
        int lane = t & 63;
        int w = t >> 6;
        int node = b * 4 + w;
        if (node < N) {
            float acc = emb_b[lane];
#pragma unroll
            for (int k = 0; k < FIN; k++) acc += x[node * FIN + k] * emb_W[k * H + lane];
            h0[(size_t)node * H + lane] = (_Float16)acc;
        }
    } else if (b < nbE + NLAYERS * LUTB) {
        int lb = b - nbE;
        int l = lb / LUTB, part = lb % LUTB;
        if (t < 64) {
            float s = 0.f;
            for (int j = 0; j < H; j++) s += fW2[l * H * H + t * H + j];
            swsum[t] = s;
        }
        if (t == 64) {
            float s = 0.f;
            for (int j = 0; j < H; j++) s += fb2[l * H + j];
            sbsum = s;
        }
        __syncthreads();
        int i = part * 256 + t;
        if (i <= LUTN) {
            float d = (float)i * (CUTOFF / (float)LUTN);
            float scaled = d * (2.0f / CUTOFF) - 1.0f;
            float cut = 0.5f * (__cosf(d * (3.14159265358979f / CUTOFF)) + 1.0f);
            if (d > CUTOFF) cut = 0.f;
            float s = 0.f;
            for (int hh = 0; hh < H; hh++) {
                int wi = l * H + hh;
                s += tanhf(scaled * fW1[wi] + fb1[wi]) * swsum[hh];
            }
            lut[l * LUTSTRIDE + i] = cut * (s + sbsum);
        }
    } else {
        int tid = (b - nbE - NLAYERS * LUTB) * 256 + t;
        if (tid < NLAYERS * H)
            b2p[tid] = ib2[tid] * BN_INV * bn_g[tid] + bn_b[tid];
        if (tid < NLAYERS * 2 * 8 * 64) {
            int lane = tid & 63;
            int frag = (tid >> 6) & 7;
            int mat  = (tid >> 9) & 1;
            int l    = tid >> 10;
            int kt = frag >> 2, nt = frag & 3;
            int n = nt * 16 + (lane & 15);
            int k0 = kt * 32 + (lane >> 4) * 8;
            const float* W = (mat ? iW2 : iW1) + l * H * H;
            float scale = mat ? BN_INV * bn_g[l * H + n] : 1.0f;
            h8 v;
#pragma unroll
            for (int j = 0; j < 8; j++) v[j] = (_Float16)(W[(k0 + j) * H + n] * scale);
            Wsw[tid] = v;
        }
    }
}

// Partitioned histogram: partition p = blockIdx%8. Atomic return value
// is the within-(partition,row) rank.
__global__ __launch_bounds__(256)
void k_hist(const int* __restrict__ ei, int* __restrict__ cnt8,
            unsigned char* __restrict__ rank8, int N, int E) {
    int e = blockIdx.x * 256 + threadIdx.x;
    if (e < E) {
        int p = blockIdx.x & (NPART - 1);
        int r = atomicAdd(&cnt8[(size_t)p * N + ei[e]], 1);
        rank8[e] = (unsigned char)r;
    }
}

// scan stage 1: per-256-row block sums of the row totals (8 partitions summed)
__global__ void k_scan1(const int* __restrict__ cnt8, int* __restrict__ bsums, int N) {
    __shared__ int sd[256];
    int i = blockIdx.x * 256 + threadIdx.x;
    int v = 0;
    if (i < N) {
#pragma unroll
        for (int p = 0; p < NPART; p++) v += cnt8[(size_t)p * N + i];
    }
    sd[threadIdx.x] = v;
    __syncthreads();
    for (int off = 128; off > 0; off >>= 1) {
        if (threadIdx.x < off) sd[threadIdx.x] += sd[threadIdx.x + off];
        __syncthreads();
    }
    if (threadIdx.x == 0) bsums[blockIdx.x] = sd[0];
}

// scan stage 2+3 fused: every block redundantly scans the <=512 block sums in
// LDS, takes its own base, then per-block scan of row totals -> row_ptr and
// per-partition bases base[p][row].
__global__ void k_scan23(const int* __restrict__ cnt8, const int* __restrict__ bsums,
                         int* __restrict__ row_ptr, int* __restrict__ base,
                         int N, int nb) {
    __shared__ int sd[256];
    __shared__ int ex[512];
    int t = threadIdx.x;
    int a0 = (2 * t     < nb) ? bsums[2 * t]     : 0;
    int a1 = (2 * t + 1 < nb) ? bsums[2 * t + 1] : 0;
    sd[t] = a0 + a1;
    __syncthreads();
    for (int off = 1; off < 256; off <<= 1) {
        int v = (t >= off) ? sd[t - off] : 0;
        __syncthreads();
        sd[t] += v;
        __syncthreads();
    }
    int pairExcl = (t == 0) ? 0 : sd[t - 1];
    ex[2 * t] = pairExcl;
    ex[2 * t + 1] = pairExcl + a0;
    __syncthreads();
    int myBase = ex[blockIdx.x];
    __syncthreads();

    int i = blockIdx.x * 256 + t;
    int c[NPART];
    int v = 0;
    if (i < N) {
#pragma unroll
        for (int p = 0; p < NPART; p++) { c[p] = cnt8[(size_t)p * N + i]; v += c[p]; }
    }
    sd[t] = v;
    __syncthreads();
    for (int off = 1; off < 256; off <<= 1) {
        int u = (t >= off) ? sd[t - off] : 0;
        __syncthreads();
        sd[t] += u;
        __syncthreads();
    }
    int excl = sd[t] - v + myBase;
    if (i < N) {
        row_ptr[i] = excl;
        int run = excl;
#pragma unroll
        for (int p = 0; p < NPART; p++) { base[(size_t)p * N + i] = run; run += c[p]; }
        if (i == N - 1) row_ptr[N] = excl + v;
    }
}

// Thread-per-edge, no atomics: pos = base[p][row] + rank8[e] (p matches k_hist).
// Pack {col:17b | d_quant:15b}; nontemporal store (avoid line allocate).
__global__ __launch_bounds__(256)
void k_scatter(const int* __restrict__ ei, const float* __restrict__ dist,
               const unsigned char* __restrict__ rank8, const int* __restrict__ base,
               unsigned int* __restrict__ recs, int N, int E) {
    int e = blockIdx.x * 256 + threadIdx.x;
    if (e >= E) return;
    int p = blockIdx.x & (NPART - 1);
    int row = ei[e], col = ei[E + e];
    float d = dist[e];
    int didx = (int)(d * (32768.0f / CUTOFF) + 0.5f);
    didx = max(0, min(didx, 32767));
    int pos = base[(size_t)p * N + row] + (int)rank8[e];
    __builtin_nontemporal_store(((unsigned)col << 15) | (unsigned)didx, &recs[pos]);
}

// Fused layer: phase A 8 groups x 8 lanes (R13 shape) with 2-wide edge unroll —
// each group keeps TWO independent rec->gather->fma chains in flight (clamped
// index, fv zeroed when out of range: loads never blocked by a branch).
// fs lerped inline from LDS LUT. Phase B: 64x64x2 MLP as 16 MFMAs (fp16, BN
// folded in W2'). fp16 h double-buffered.
__global__ __launch_bounds__(256)
void k_layer(const int* __restrict__ row_ptr, const unsigned int* __restrict__ recs,
             const float* __restrict__ lutl, const h8* __restrict__ Wsw,
             const float* __restrict__ b1, const float* __restrict__ b2p,
             const _Float16* __restrict__ h_in, _Float16* __restrict__ h_out,
             int N) {
    __shared__ float s_lut[LUTN + 1];       // 8196 B
    __shared__ _Float16 sA[64 * ASTRIDE];   // 9216 B
    for (int i = threadIdx.x; i <= LUTN; i += 256) s_lut[i] = lutl[i];
    __syncthreads();

    int lane = threadIdx.x & 63;
    int w = threadIdx.x >> 6;
    int base = blockIdx.x * 64 + w * 16;    // this wave's 16 nodes
    int g = lane >> 3, ci = lane & 7;       // 8 groups x 8 lanes
    const uint4* h4 = (const uint4*)h_in;   // 8 halves per uint4; 8 per row

    // ---- phase A: aggregate (packed fp16, 2 edges in flight per group) ----
    for (int i = 0; i < 16; i++) {
        int node = base + i;
        h2 acc[4];
#pragma unroll
        for (int q = 0; q < 4; q++) acc[q] = (h2){(_Float16)0.f, (_Float16)0.f};
        if (node < N) {
            int s = row_ptr[node], t = row_ptr[node + 1];
            for (int k = s + g; k < t; k += 16) {
                int kb = k + 8;
                bool v2 = kb < t;
                int kbc = v2 ? kb : k;          // clamped: always a valid index
                unsigned rec0 = recs[k];
                unsigned rec1 = recs[kbc];
                int c0 = rec0 >> 15;
                int c1 = rec1 >> 15;
                // fv decode for both edges
                float td0 = (float)(rec0 & 32767u) * (1.0f / 16.0f);
                float td1 = (float)(rec1 & 32767u) * (1.0f / 16.0f);
                int i00 = (int)td0, i01 = (int)td1;
                float fr0 = td0 - (float)i00, fr1 = td1 - (float)i01;
                float f00 = s_lut[i00], f01 = s_lut[i01];
                float fv0 = f00 + fr0 * (s_lut[i00 + 1] - f00);
                float fv1 = f01 + fr1 * (s_lut[i01 + 1] - f01);
                fv1 = v2 ? fv1 : 0.f;
                _Float16 fh0 = (_Float16)fv0, fh1 = (_Float16)fv1;
                h2 fva = (h2){fh0, fh0};
                h2 fvb = (h2){fh1, fh1};
                union { uint4 u; h2 v[4]; } p0, p1;
                p0.u = h4[(size_t)c0 * 8 + ci];
                p1.u = h4[(size_t)c1 * 8 + ci];
#pragma unroll
                for (int q = 0; q < 4; q++) acc[q] += fva * p0.v[q];
#pragma unroll
                for (int q = 0; q < 4; q++) acc[q] += fvb * p1.v[q];
            }
        }
#pragma unroll
        for (int m = 8; m <= 32; m <<= 1) {
#pragma unroll
            for (int q = 0; q < 4; q++) {
                union { h2 v; int u; } a, b;
                a.v = acc[q];
                b.u = __shfl_xor(a.u, m, 64);
                acc[q] += b.v;
            }
        }
        if (g == 0) {
            union { uint4 u4; h2 v[4]; } pk;
#pragma unroll
            for (int q = 0; q < 4; q++) pk.v[q] = acc[q];
            *(uint4*)&sA[(size_t)(w * 16 + i) * ASTRIDE + ci * 8] = pk.u4;
        }
    }
    // wave-private LDS rows: in-wave ds ordering, no barrier needed

    // ---- phase B: MFMA MLP ----
    int q4 = lane >> 4, c16 = lane & 15;
    int rowb = w * 16;
    const h8* WB1 = Wsw;            // frags [kt][nt][lane]
    const h8* WB2 = Wsw + 8 * 64;
    h8 A0 = *(const h8*)&sA[(size_t)(rowb + c16) * ASTRIDE + q4 * 8];
    h8 A1 = *(const h8*)&sA[(size_t)(rowb + c16) * ASTRIDE + 32 + q4 * 8];
    f32x4 C1[4];
#pragma unroll
    for (int nt = 0; nt < 4; nt++) {
        f32x4 c = {0.f, 0.f, 0.f, 0.f};
        c = __builtin_amdgcn_mfma_f32_16x16x32_f16(A0, WB1[nt * 64 + lane], c, 0, 0, 0);
        c = __builtin_amdgcn_mfma_f32_16x16x32_f16(A1, WB1[(4 + nt) * 64 + lane], c, 0, 0, 0);
        C1[nt] = c;
    }
#pragma unroll
    for (int nt = 0; nt < 4; nt++) {
        float bb = b1[nt * 16 + c16];
#pragma unroll
        for (int reg = 0; reg < 4; reg++) {
            float v = softplus_f(C1[nt][reg] + bb);
            sA[(size_t)(rowb + q4 * 4 + reg) * ASTRIDE + nt * 16 + c16] = (_Float16)v;
        }
    }
    h8 M0 = *(const h8*)&sA[(size_t)(rowb + c16) * ASTRIDE + q4 * 8];
    h8 M1 = *(const h8*)&sA[(size_t)(rowb + c16) * ASTRIDE + 32 + q4 * 8];
    f32x4 C2[4];
#pragma unroll
    for (int nt = 0; nt < 4; nt++) {
        f32x4 c = {0.f, 0.f, 0.f, 0.f};
        c = __builtin_amdgcn_mfma_f32_16x16x32_f16(M0, WB2[nt * 64 + lane], c, 0, 0, 0);
        c = __builtin_amdgcn_mfma_f32_16x16x32_f16(M1, WB2[(4 + nt) * 64 + lane], c, 0, 0, 0);
        C2[nt] = c;
    }
    // epilogue: + b2' (BN folded), fp16 residual, dbuf write
#pragma unroll
    for (int nt = 0; nt < 4; nt++) {
        float bb2 = b2p[nt * 16 + c16];
#pragma unroll
        for (int reg = 0; reg < 4; reg++) {
            int node = base + q4 * 4 + reg;
            if (node < N) {
                size_t idx = (size_t)node * H + nt * 16 + c16;
                float hn = (float)h_in[idx] + C2[nt][reg] + bb2;
                h_out[idx] = (_Float16)hn;
            }
        }
    }
}

// Stage 1 of mean: per-block partial sums to DISTINCT rows — no atomics.
__global__ __launch_bounds__(256)
void k_mean(const _Float16* __restrict__ hb, float* __restrict__ partials, int N) {
    __shared__ float s_r[4][H];
    int lane = threadIdx.x & 63;
    int w = threadIdx.x >> 6;
    int wg = blockIdx.x * 4 + w;
    int stride = gridDim.x * 4;
    float local = 0.f;
    for (int i = wg; i < N; i += stride) local += (float)hb[(size_t)i * H + lane];
    s_r[w][lane] = local;
    __syncthreads();
    if (w == 0) {
        float s = s_r[0][lane] + s_r[1][lane] + s_r[2][lane] + s_r[3][lane];
        partials[(size_t)blockIdx.x * H + lane] = s;
    }
}

// Stage 2: one block reduces MEANB partial rows, then the tiny output MLP.
__global__ __launch_bounds__(256)
void k_final(const float* __restrict__ partials, int N,
             const float* __restrict__ oW1, const float* __restrict__ ob1,
             const float* __restrict__ og1, const float* __restrict__ obt1,
             const float* __restrict__ oW2, const float* __restrict__ ob2,
             const float* __restrict__ og2, const float* __restrict__ obt2,
             const float* __restrict__ fin_W, const float* __restrict__ fin_b,
             float* __restrict__ out) {
    __shared__ float red[4][H];
    __shared__ float sg[H], su[H / 2], sv[H / 2];
    int t = threadIdx.x;
    int ch = t & 63, grp = t >> 6;
    float s = 0.f;
    for (int b = grp; b < MEANB; b += 4) s += partials[(size_t)b * H + ch];
    red[grp][ch] = s;
    __syncthreads();
    if (t < H) sg[t] = (red[0][t] + red[1][t] + red[2][t] + red[3][t]) / (float)N;
    __syncthreads();
    int j = t;
    if (j < H / 2) {
        float acc = ob1[j];
        for (int k = 0; k < H; k++) acc += sg[k] * oW1[k * (H / 2) + j];
        su[j] = softplus_f(acc) * BN_INV * og1[j] + obt1[j];
    }
    __syncthreads();
    if (j < H / 2) {
        float acc = ob2[j];
        for (int k = 0; k < H / 2; k++) acc += su[k] * oW2[k * (H / 2) + j];
        sv[j] = softplus_f(acc) * BN_INV * og2[j] + obt2[j];
    }
    __syncthreads();
    if (j < 3) {
        float acc = fin_b[j];
        for (int k = 0; k < H / 2; k++) acc += sv[k] * fin_W[k * 3 + j];
        out[j] = acc;
    }
}

extern "C" void kernel_launch(void* const* d_in, const int* in_sizes, int n_in,
                              void* d_out, int out_size, void* d_ws, size_t ws_size,
                              hipStream_t stream) {
    const float* x      = (const float*)d_in[0];
    const int*   ei     = (const int*)d_in[1];
    const float* dist   = (const float*)d_in[2];
    /* d_in[3] edge_attr: unused by reference */
    const float* emb_W  = (const float*)d_in[4];
    const float* emb_b  = (const float*)d_in[5];
    const float* fW1    = (const float*)d_in[6];
    const float* fb1    = (const float*)d_in[7];
    const float* fW2    = (const float*)d_in[8];
    const float* fb2    = (const float*)d_in[9];
    const float* iW1    = (const float*)d_in[10];
    const float* ib1    = (const float*)d_in[11];
    const float* iW2    = (const float*)d_in[12];
    const float* ib2    = (const float*)d_in[13];
    const float* bn_g   = (const float*)d_in[14];
    const float* bn_b   = (const float*)d_in[15];
    const float* oW1    = (const float*)d_in[16];
    const float* ob1    = (const float*)d_in[17];
    const float* og1    = (const float*)d_in[18];
    const float* obt1   = (const float*)d_in[19];
    const float* oW2    = (const float*)d_in[20];
    const float* ob2    = (const float*)d_in[21];
    const float* og2    = (const float*)d_in[22];
    const float* obt2   = (const float*)d_in[23];
    const float* fin_W  = (const float*)d_in[24];
    const float* fin_b  = (const float*)d_in[25];
    float* out = (float*)d_out;

    int N = in_sizes[0] / FIN;
    int E = in_sizes[2];
    int nb_scan = (N + 255) / 256;
    int nb_edge = (E + 255) / 256;

    // workspace layout (16B-aligned chunks first)
    float*  ws   = (float*)d_ws;
    _Float16* h0 = (_Float16*)ws;                          // N*H fp16
    _Float16* h1 = h0 + (size_t)N * H;                     // N*H fp16
    unsigned int*  recs = (unsigned int*)(h1 + (size_t)N * H);   // E uint32
    h8*     Wsw  = (h8*)(recs + E);                        // 3*2*8*64 h8
    float*  lut  = (float*)(Wsw + NLAYERS * 2 * 8 * 64);   // 3*LUTSTRIDE
    float*  partials = lut + 3 * LUTSTRIDE;                // MEANB*H
    float*  b2p  = partials + MEANB * H;                   // L*H
    int*    cnt8 = (int*)(b2p + NLAYERS * H);              // NPART*N
    int*    basep = cnt8 + (size_t)NPART * N;              // NPART*N
    int*    row_ptr = basep + (size_t)NPART * N;           // N+1
    int*    bsums   = row_ptr + (N + 1);                   // nb_scan (<=512)
    unsigned char* rank8 = (unsigned char*)(bsums + 512);  // E bytes

    int nbE = (N + 3) / 4;
    int nb_setup = nbE + NLAYERS * LUTB + 12;
    k_setup<<<nb_setup, 256, 0, stream>>>(x, emb_W, emb_b, h0,
                                          fW1, fb1, fW2, fb2, iW1, iW2,
                                          bn_g, bn_b, ib2, Wsw, b2p, lut,
                                          cnt8, N);

    k_hist<<<nb_edge, 256, 0, stream>>>(ei, cnt8, rank8, N, E);
    k_scan1<<<nb_scan, 256, 0, stream>>>(cnt8, bsums, N);
    k_scan23<<<nb_scan, 256, 0, stream>>>(cnt8, bsums, row_ptr, basep, N, nb_scan);

    k_scatter<<<nb_edge, 256, 0, stream>>>(ei, dist, rank8, basep, recs, N, E);

    _Float16* hp[2] = {h0, h1};
    int nb_tile = (N + 63) / 64;
    for (int l = 0; l < NLAYERS; l++) {
        k_layer<<<nb_tile, 256, 0, stream>>>(row_ptr, recs, lut + (size_t)l * LUTSTRIDE,
                                             Wsw + (size_t)l * 1024,
                                             ib1 + l * H, b2p + l * H,
                                             hp[l & 1], hp[(l + 1) & 1], N);
    }
    _Float16* h_final = hp[NLAYERS & 1];

    k_mean<<<MEANB, 256, 0, stream>>>(h_final, partials, N);
    k_final<<<1, 256, 0, stream>>>(partials, N, oW1, ob1, og1, obt1,
                                   oW2, ob2, og2, obt2, fin_W, fin_b, out);
}